// Round 2
// baseline (110.421 us; speedup 1.0000x reference)
//
#include <hip/hip_runtime.h>
#include <hip/hip_cooperative_groups.h>
#include <math.h>

#define TPB 256
#define WPB (TPB / 64)
#define NBLK 256   // 1 block/CU -> cooperative co-residency guaranteed

namespace cg = cooperative_groups;

// Per-wave sample accumulation. One 64-lane wave per sample in the D=256 fast
// path: lane l loads scores[b][4l..4l+3] as one float4 (1 KiB/wave, ideal
// coalescing); idx + positive scores are wave-uniform -> scalar broadcasts.
__device__ inline void accum_waves(const float* __restrict__ scores,
                                   const int*   __restrict__ idx,
                                   int D, int total_scores, int total_idx,
                                   int gw, int gstride, int lane,
                                   float& loss, float& pairs) {
    const bool fast = (D == 256) &&
                      ((total_scores & 255) == 0) &&
                      ((long long)total_idx * 32LL == (long long)total_scores);

    if (fast) {
        const int B = total_scores >> 8;
        for (int b = gw; b < B; b += gstride) {
            const int rb = b << 8;
            const int ib = b << 3;

            const int4 i0 = *reinterpret_cast<const int4*>(idx + ib);
            const int4 i1 = *reinterpret_cast<const int4*>(idx + ib + 4);
            int ik[8] = { i0.x, i0.y, i0.z, i0.w, i1.x, i1.y, i1.z, i1.w };

            const float4 v = *reinterpret_cast<const float4*>(scores + rb + (lane << 2));

            float c[8];                 // c[k] = 1 - s_pos[k], -inf if duplicate
            int P = 0;
            #pragma unroll
            for (int k = 0; k < 8; ++k) {
                bool dup = false;
                #pragma unroll
                for (int j = 0; j < 8; ++j)
                    if (j < k) dup |= (ik[j] == ik[k]);
                const float pscore = scores[rb + ik[k]];
                if (!dup) { ++P; c[k] = 1.0f - pscore; }
                else      { c[k] = -INFINITY; }
            }

            const int e0 = lane << 2;
            const float se[4] = { v.x, v.y, v.z, v.w };
            #pragma unroll
            for (int j = 0; j < 4; ++j) {
                const int e = e0 + j;
                bool pos = false;
                #pragma unroll
                for (int k = 0; k < 8; ++k) pos |= (ik[k] == e);
                const float s = pos ? -INFINITY : se[j];
                #pragma unroll
                for (int k = 0; k < 8; ++k)
                    loss += fmaxf(0.0f, s + c[k]);   // relu(s_n - s_p + margin)
            }
            if (lane == 0) pairs += (float)((256 - P) * P);
        }
    } else if (D > 0) {
        const int B = total_scores / D;
        const int K = (B > 0) ? (total_idx / B) : 0;
        for (int b = gw; b < B; b += gstride) {
            const int rb = b * D, ib = b * K;
            int P = 0;
            for (int k = 0; k < K; ++k) {
                bool dup = false;
                for (int j = 0; j < k; ++j) dup |= (idx[ib + j] == idx[ib + k]);
                if (!dup) ++P;
            }
            for (int d = lane; d < D; d += 64) {
                const float s = scores[rb + d] + 1.0f;
                bool pos = false;
                for (int k = 0; k < K; ++k) pos |= (idx[ib + k] == d);
                if (!pos) {
                    for (int k = 0; k < K; ++k) {
                        bool dup = false;
                        for (int j = 0; j < k; ++j) dup |= (idx[ib + j] == idx[ib + k]);
                        if (!dup) {
                            const float t = s - scores[rb + idx[ib + k]];
                            loss += (t > 0.0f) ? t : 0.0f;
                        }
                    }
                }
            }
            if (lane == 0) pairs += (float)((D - P) * P);
        }
    }
}

// Block partial -> LDS combine; returns (loss, pairs) valid on thread 0.
__device__ inline float2 block_reduce(float loss, float pairs, int lane, int wv) {
    #pragma unroll
    for (int off = 32; off > 0; off >>= 1)
        loss += __shfl_down(loss, off, 64);
    // pairs only ever accumulated on lane 0 of each wave
    __shared__ float2 red[WPB];
    if (lane == 0) red[wv] = make_float2(loss, pairs);
    __syncthreads();
    float2 acc = make_float2(0.f, 0.f);
    if (threadIdx.x == 0) {
        acc = red[0];
        #pragma unroll
        for (int w = 1; w < WPB; ++w) { acc.x += red[w].x; acc.y += red[w].y; }
    }
    return acc;
}

// ---- single cooperative kernel: no workspace init needed (write-before-read)
__global__ __launch_bounds__(TPB) void mlrl_coop(
        const float* __restrict__ scores,
        const int*   __restrict__ idx,
        const int*   __restrict__ ndev,
        int total_scores, int total_idx,
        float2* __restrict__ partials,
        float*  __restrict__ out) {

    const int D    = *ndev;
    const int lane = threadIdx.x & 63;
    const int wv   = __builtin_amdgcn_readfirstlane((int)threadIdx.x) >> 6;

    float loss = 0.0f, pairs = 0.0f;
    accum_waves(scores, idx, D, total_scores, total_idx,
                blockIdx.x * WPB + wv, gridDim.x * WPB, lane, loss, pairs);

    const float2 bp = block_reduce(loss, pairs, lane, wv);
    if (threadIdx.x == 0) partials[blockIdx.x] = bp;
    __threadfence();                      // make partial visible device-wide
    cg::this_grid().sync();

    if (blockIdx.x == 0) {
        double l = 0.0, p = 0.0;
        for (int i = threadIdx.x; i < (int)gridDim.x; i += TPB) {
            const float2 v = partials[i];
            l += (double)v.x;
            p += (double)v.y;
        }
        #pragma unroll
        for (int off = 32; off > 0; off >>= 1) {
            l += __shfl_down(l, off, 64);
            p += __shfl_down(p, off, 64);
        }
        __shared__ double sl[WPB], sp[WPB];
        if (lane == 0) { sl[wv] = l; sp[wv] = p; }
        __syncthreads();
        if (threadIdx.x == 0) {
            double L = 0.0, P = 0.0;
            #pragma unroll
            for (int w = 0; w < WPB; ++w) { L += sl[w]; P += sp[w]; }
            out[0] = (P > 0.0) ? (float)(L / (P < 1.0 ? 1.0 : P)) : 0.0f;
        }
    }
}

// ---- fallback (non-cooperative) path: two kernels, no ws init needed ----
__global__ __launch_bounds__(TPB) void mlrl_main(
        const float* __restrict__ scores,
        const int*   __restrict__ idx,
        const int*   __restrict__ ndev,
        int total_scores, int total_idx,
        float2* __restrict__ partials) {
    const int D    = *ndev;
    const int lane = threadIdx.x & 63;
    const int wv   = __builtin_amdgcn_readfirstlane((int)threadIdx.x) >> 6;
    float loss = 0.0f, pairs = 0.0f;
    accum_waves(scores, idx, D, total_scores, total_idx,
                blockIdx.x * WPB + wv, gridDim.x * WPB, lane, loss, pairs);
    const float2 bp = block_reduce(loss, pairs, lane, wv);
    if (threadIdx.x == 0) partials[blockIdx.x] = bp;
}

__global__ __launch_bounds__(TPB) void mlrl_finalize(
        const float2* __restrict__ partials, int n, float* __restrict__ out) {
    const int lane = threadIdx.x & 63;
    const int wv   = __builtin_amdgcn_readfirstlane((int)threadIdx.x) >> 6;
    double l = 0.0, p = 0.0;
    for (int i = threadIdx.x; i < n; i += TPB) {
        const float2 v = partials[i];
        l += (double)v.x;
        p += (double)v.y;
    }
    #pragma unroll
    for (int off = 32; off > 0; off >>= 1) {
        l += __shfl_down(l, off, 64);
        p += __shfl_down(p, off, 64);
    }
    __shared__ double sl[WPB], sp[WPB];
    if (lane == 0) { sl[wv] = l; sp[wv] = p; }
    __syncthreads();
    if (threadIdx.x == 0) {
        double L = 0.0, P = 0.0;
        #pragma unroll
        for (int w = 0; w < WPB; ++w) { L += sl[w]; P += sp[w]; }
        out[0] = (P > 0.0) ? (float)(L / (P < 1.0 ? 1.0 : P)) : 0.0f;
    }
}

extern "C" void kernel_launch(void* const* d_in, const int* in_sizes, int n_in,
                              void* d_out, int out_size, void* d_ws, size_t ws_size,
                              hipStream_t stream) {
    const float* scores = (const float*)d_in[0];
    const int*   idx    = (const int*)d_in[1];
    const int*   ndev   = (const int*)d_in[2];
    float*       out    = (float*)d_out;

    int total_scores = in_sizes[0];  // B*D
    int total_idx    = in_sizes[1];  // B*K
    float2* partials = (float2*)d_ws;

    void* args[] = { (void*)&scores, (void*)&idx, (void*)&ndev,
                     (void*)&total_scores, (void*)&total_idx,
                     (void*)&partials, (void*)&out };

    hipError_t err = hipLaunchCooperativeKernel(
        (const void*)mlrl_coop, dim3(NBLK), dim3(TPB), args, 0, stream);

    if (err != hipSuccess) {
        // Fallback: classic two-kernel reduction (no ws init required).
        int nblk = NBLK;
        if ((size_t)nblk * sizeof(float2) > ws_size)
            nblk = (int)(ws_size / sizeof(float2));
        if (nblk < 1) nblk = 1;
        mlrl_main<<<nblk, TPB, 0, stream>>>(scores, idx, ndev,
                                            total_scores, total_idx, partials);
        mlrl_finalize<<<1, TPB, 0, stream>>>(partials, nblk, out);
    }
}

// Round 3
// 61.269 us; speedup vs baseline: 1.8022x; 1.8022x over previous
//
#include <hip/hip_runtime.h>
#include <math.h>

#define TPB 256
#define WPB (TPB / 64)

// Per-wave sample accumulation. One 64-lane wave per sample in the D=256 fast
// path: lane l loads scores[b][4l..4l+3] as one float4 (1 KiB/wave, ideal
// coalescing); idx + positive scores are wave-uniform -> scalar broadcasts.
__device__ inline void accum_waves(const float* __restrict__ scores,
                                   const int*   __restrict__ idx,
                                   int D, int total_scores, int total_idx,
                                   int gw, int gstride, int lane,
                                   float& loss, float& pairs) {
    const bool fast = (D == 256) &&
                      ((total_scores & 255) == 0) &&
                      ((long long)total_idx * 32LL == (long long)total_scores);

    if (fast) {
        const int B = total_scores >> 8;          // bench: 2048 (one trip/wave)
        for (int b = gw; b < B; b += gstride) {
            const int rb = b << 8;
            const int ib = b << 3;

            const int4 i0 = *reinterpret_cast<const int4*>(idx + ib);
            const int4 i1 = *reinterpret_cast<const int4*>(idx + ib + 4);
            int ik[8] = { i0.x, i0.y, i0.z, i0.w, i1.x, i1.y, i1.z, i1.w };

            const float4 v = *reinterpret_cast<const float4*>(scores + rb + (lane << 2));

            float c[8];                 // c[k] = 1 - s_pos[k], -inf if duplicate
            int P = 0;
            #pragma unroll
            for (int k = 0; k < 8; ++k) {
                bool dup = false;
                #pragma unroll
                for (int j = 0; j < 8; ++j)
                    if (j < k) dup |= (ik[j] == ik[k]);
                const float pscore = scores[rb + ik[k]];
                if (!dup) { ++P; c[k] = 1.0f - pscore; }
                else      { c[k] = -INFINITY; }
            }

            const int e0 = lane << 2;
            const float se[4] = { v.x, v.y, v.z, v.w };
            #pragma unroll
            for (int j = 0; j < 4; ++j) {
                const int e = e0 + j;
                bool pos = false;
                #pragma unroll
                for (int k = 0; k < 8; ++k) pos |= (ik[k] == e);
                const float s = pos ? -INFINITY : se[j];
                #pragma unroll
                for (int k = 0; k < 8; ++k)
                    loss += fmaxf(0.0f, s + c[k]);   // relu(s_n - s_p + margin)
            }
            if (lane == 0) pairs += (float)((256 - P) * P);
        }
    } else if (D > 0) {
        // Generic runtime-D/K fallback (not hit by the bench shape).
        const int B = total_scores / D;
        const int K = (B > 0) ? (total_idx / B) : 0;
        for (int b = gw; b < B; b += gstride) {
            const int rb = b * D, ib = b * K;
            int P = 0;
            for (int k = 0; k < K; ++k) {
                bool dup = false;
                for (int j = 0; j < k; ++j) dup |= (idx[ib + j] == idx[ib + k]);
                if (!dup) ++P;
            }
            for (int d = lane; d < D; d += 64) {
                const float s = scores[rb + d] + 1.0f;
                bool pos = false;
                for (int k = 0; k < K; ++k) pos |= (idx[ib + k] == d);
                if (!pos) {
                    for (int k = 0; k < K; ++k) {
                        bool dup = false;
                        for (int j = 0; j < k; ++j) dup |= (idx[ib + j] == idx[ib + k]);
                        if (!dup) {
                            const float t = s - scores[rb + idx[ib + k]];
                            loss += (t > 0.0f) ? t : 0.0f;
                        }
                    }
                }
            }
            if (lane == 0) pairs += (float)((D - P) * P);
        }
    }
}

// ---- kernel 1: per-block partials (write-before-read -> no ws init) ----
__global__ __launch_bounds__(TPB) void mlrl_main(
        const float* __restrict__ scores,
        const int*   __restrict__ idx,
        const int*   __restrict__ ndev,
        int total_scores, int total_idx,
        float2* __restrict__ partials) {
    const int D    = *ndev;
    const int lane = threadIdx.x & 63;
    const int wv   = __builtin_amdgcn_readfirstlane((int)threadIdx.x) >> 6;

    float loss = 0.0f, pairs = 0.0f;
    accum_waves(scores, idx, D, total_scores, total_idx,
                blockIdx.x * WPB + wv, gridDim.x * WPB, lane, loss, pairs);

    // wave reduce (loss only; pairs lives on lane 0 of each wave already)
    #pragma unroll
    for (int off = 32; off > 0; off >>= 1)
        loss += __shfl_down(loss, off, 64);

    __shared__ float2 red[WPB];
    if (lane == 0) red[wv] = make_float2(loss, pairs);
    __syncthreads();
    if (threadIdx.x == 0) {
        float2 acc = red[0];
        #pragma unroll
        for (int w = 1; w < WPB; ++w) { acc.x += red[w].x; acc.y += red[w].y; }
        partials[blockIdx.x] = acc;
    }
}

// ---- kernel 2: reduce partials, write scalar ----
__global__ __launch_bounds__(TPB) void mlrl_finalize(
        const float2* __restrict__ partials, int n, float* __restrict__ out) {
    const int lane = threadIdx.x & 63;
    const int wv   = __builtin_amdgcn_readfirstlane((int)threadIdx.x) >> 6;
    double l = 0.0, p = 0.0;
    for (int i = threadIdx.x; i < n; i += TPB) {
        const float2 v = partials[i];
        l += (double)v.x;
        p += (double)v.y;
    }
    #pragma unroll
    for (int off = 32; off > 0; off >>= 1) {
        l += __shfl_down(l, off, 64);
        p += __shfl_down(p, off, 64);
    }
    __shared__ double sl[WPB], sp[WPB];
    if (lane == 0) { sl[wv] = l; sp[wv] = p; }
    __syncthreads();
    if (threadIdx.x == 0) {
        double L = 0.0, P = 0.0;
        #pragma unroll
        for (int w = 0; w < WPB; ++w) { L += sl[w]; P += sp[w]; }
        out[0] = (P > 0.0) ? (float)(L / (P < 1.0 ? 1.0 : P)) : 0.0f;
    }
}

extern "C" void kernel_launch(void* const* d_in, const int* in_sizes, int n_in,
                              void* d_out, int out_size, void* d_ws, size_t ws_size,
                              hipStream_t stream) {
    const float* scores = (const float*)d_in[0];
    const int*   idx    = (const int*)d_in[1];
    const int*   ndev   = (const int*)d_in[2];
    float*       out    = (float*)d_out;

    const int total_scores = in_sizes[0];  // B*D
    const int total_idx    = in_sizes[1];  // B*K

    // 4 waves/block, 1 sample/wave at D=256 -> 1024 score elems per block.
    int nblk = total_scores >> 10;
    if (nblk < 1)    nblk = 1;
    if (nblk > 2048) nblk = 2048;
    if ((size_t)nblk * sizeof(float2) > ws_size)
        nblk = (int)(ws_size / sizeof(float2));
    if (nblk < 1) nblk = 1;

    float2* partials = (float2*)d_ws;

    mlrl_main<<<nblk, TPB, 0, stream>>>(scores, idx, ndev,
                                        total_scores, total_idx, partials);
    mlrl_finalize<<<1, TPB, 0, stream>>>(partials, nblk, out);
}